// Round 5
// baseline (80.562 us; speedup 1.0000x reference)
//
#include <hip/hip_runtime.h>
#include <stdint.h>

// Fused softmax + top-8 (renormalized) over 64 experts.
// Layout: 1 wave = 8 tokens/iter; 8 lanes per token; 8 logits per lane.
// Persistent waves, 2-deep software pipeline: load tile i+1 -> compute tile i.
// Keys: exact f64 = (double)(monotonic_u32(logit)) + (63-expert_idx)/64
//   -> exact ordering, ties -> lower expert index (jax.lax.top_k stable).
// Selection: per-lane sort-8 + 3-level symmetric bitonic merge via DPP.

typedef float f32x4 __attribute__((ext_vector_type(4)));

#define DPP_QUAD_XOR1   0xB1   // quad_perm(1,0,3,2)  : lane ^ 1
#define DPP_QUAD_XOR2   0x4E   // quad_perm(2,3,0,1)  : lane ^ 2
#define DPP_HALF_MIRROR 0x141  // row_half_mirror     : lane <-> 7-lane (in 8)

template<int CTRL>
static __device__ __forceinline__ double dpp64d(double x) {
    uint64_t b = (uint64_t)__double_as_longlong(x);
    int lo = __builtin_amdgcn_update_dpp(0, (int)(uint32_t)b,         CTRL, 0xF, 0xF, true);
    int hi = __builtin_amdgcn_update_dpp(0, (int)(uint32_t)(b >> 32), CTRL, 0xF, 0xF, true);
    uint64_t r = ((uint64_t)(uint32_t)hi << 32) | (uint32_t)lo;
    return __longlong_as_double((long long)r);
}

template<int CTRL>
static __device__ __forceinline__ float dppf(float x) {
    int i = __builtin_amdgcn_update_dpp(0, __float_as_int(x), CTRL, 0xF, 0xF, true);
    return __int_as_float(i);
}

// compare-exchange, descending (max stays in x): v_max_f64 + v_min_f64
#define CED(x, y) { double hi_ = fmax(x, y), lo_ = fmin(x, y); x = hi_; y = lo_; }

template<int CTRL>
static __device__ __forceinline__ void merge_level(double k[8]) {
    // m[i] = max(own[i], partner[7-i]) -> top-8 of union, bitonic; then clean.
    double m[8];
#pragma unroll
    for (int i = 0; i < 8; ++i) {
        double p = dpp64d<CTRL>(k[7 - i]);
        m[i] = fmax(k[i], p);
    }
    CED(m[0], m[4]) CED(m[1], m[5]) CED(m[2], m[6]) CED(m[3], m[7])
    CED(m[0], m[2]) CED(m[1], m[3]) CED(m[4], m[6]) CED(m[5], m[7])
    CED(m[0], m[1]) CED(m[2], m[3]) CED(m[4], m[5]) CED(m[6], m[7])
#pragma unroll
    for (int i = 0; i < 8; ++i) k[i] = m[i];
}

__global__ __launch_bounds__(256) void topk_softmax_k(
    const float* __restrict__ logits,
    float* __restrict__ out_w,
    float* __restrict__ out_id,
    float* __restrict__ out_tei,
    int T)
{
    const int lane = threadIdx.x & 63;
    const int wv   = (int)(threadIdx.x >> 6);
    const int sub  = lane & 7;

    const long ng = ((long)T + 7) >> 3;                       // token groups of 8
    const long gs = (long)gridDim.x * 4;                      // total waves
    long g = (long)blockIdx.x * 4 + wv;
    if (g >= ng) return;

    const f32x4* __restrict__ base = reinterpret_cast<const f32x4*>(logits);
    const double kbase = (double)(63 - sub * 8) * 0.015625;   // cidx0/64, exact

    // prologue: load first tile
    f32x4 a0 = __builtin_nontemporal_load(base + g * 128 + lane * 2);
    f32x4 b0 = __builtin_nontemporal_load(base + g * 128 + lane * 2 + 1);

    while (g < ng) {
        // ---- issue next tile's loads (hidden under this tile's compute) ----
        const long gn  = g + gs;
        const long gnc = (gn < ng) ? gn : g;                  // wave-uniform clamp
        f32x4 a1 = __builtin_nontemporal_load(base + gnc * 128 + lane * 2);
        f32x4 b1 = __builtin_nontemporal_load(base + gnc * 128 + lane * 2 + 1);

        // ---- build exact f64 keys ----
        const float vals[8] = {a0.x, a0.y, a0.z, a0.w, b0.x, b0.y, b0.z, b0.w};
        double k[8];
#pragma unroll
        for (int j = 0; j < 8; ++j) {
            uint32_t u = __float_as_uint(vals[j]);
            uint32_t o = (u & 0x80000000u) ? ~u : (u | 0x80000000u);  // monotonic
            k[j] = (double)o + (kbase - j * 0.015625);                 // exact dyadic
        }

        // ---- sort lane's 8 keys descending (Batcher, 19 CE) ----
        CED(k[0],k[1]) CED(k[2],k[3]) CED(k[4],k[5]) CED(k[6],k[7])
        CED(k[0],k[2]) CED(k[1],k[3]) CED(k[4],k[6]) CED(k[5],k[7])
        CED(k[1],k[2]) CED(k[5],k[6])
        CED(k[0],k[4]) CED(k[1],k[5]) CED(k[2],k[6]) CED(k[3],k[7])
        CED(k[2],k[4]) CED(k[3],k[5])
        CED(k[1],k[2]) CED(k[3],k[4]) CED(k[5],k[6])

        // ---- 3-level symmetric merge: all 8 lanes end with global top-8 ----
        merge_level<DPP_QUAD_XOR1>(k);
        merge_level<DPP_QUAD_XOR2>(k);
        merge_level<DPP_HALF_MIRROR>(k);

        // ---- lane `sub` takes slot `sub` (static-index select tree) ----
        double t4a = (sub & 4) ? k[4] : k[0];
        double t4b = (sub & 4) ? k[5] : k[1];
        double t4c = (sub & 4) ? k[6] : k[2];
        double t4d = (sub & 4) ? k[7] : k[3];
        double t2a = (sub & 2) ? t4c : t4a;
        double t2b = (sub & 2) ? t4d : t4b;
        double sel = (sub & 1) ? t2b : t2a;

        // decode max (slot 0) value
        uint32_t o0 = (uint32_t)k[0];
        uint32_t mb = (o0 & 0x80000000u) ? (o0 & 0x7fffffffu) : ~o0;
        float    mv = __uint_as_float(mb);

        // decode own slot (value, index)
        uint32_t os   = (uint32_t)sel;               // trunc = floor (sel > 0)
        double   frac = sel - (double)os;
        int      cidx = (int)(frac * 64.0 + 0.5);    // exact integer
        int      idx  = 63 - cidx;
        uint32_t ub   = (os & 0x80000000u) ? (os & 0x7fffffffu) : ~os;
        float    v    = __uint_as_float(ub);

        // ---- renormalized softmax over the selected 8 ----
        float e = __expf(v - mv);
        float s = e;
        s += dppf<DPP_QUAD_XOR1>(s);
        s += dppf<DPP_QUAD_XOR2>(s);
        s += dppf<DPP_HALF_MIRROR>(s);
        float wgt = e * __builtin_amdgcn_rcpf(s);

        // ---- store (3 coalesced dword streams) ----
        const long t0 = g * 8;
        if (t0 + (lane >> 3) < T) {
            const long oi = t0 * 8 + lane;
            __builtin_nontemporal_store(wgt,        &out_w[oi]);
            __builtin_nontemporal_store((float)idx, &out_id[oi]);
            __builtin_nontemporal_store((float)oi,  &out_tei[oi]);
        }

        a0 = a1; b0 = b1;
        g = gn;
    }
}

extern "C" void kernel_launch(void* const* d_in, const int* in_sizes, int n_in,
                              void* d_out, int out_size, void* d_ws, size_t ws_size,
                              hipStream_t stream) {
    const float* logits = (const float*)d_in[0];
    const int T = in_sizes[0] / 64;

    float* outw = (float*)d_out;
    float* outi = outw + (size_t)T * 8;
    float* outt = outi + (size_t)T * 8;

    const long ng = ((long)T + 7) >> 3;
    long blocks = 2048;                       // persistent: ~8 blocks/CU
    if (blocks > (ng + 3) / 4) blocks = (ng + 3) / 4;
    hipLaunchKernelGGL(topk_softmax_k, dim3((uint32_t)blocks), dim3(256), 0, stream,
                       logits, outw, outi, outt, T);
}